// Round 1
// baseline (902.460 us; speedup 1.0000x reference)
//
#include <hip/hip_runtime.h>
#include <hip/hip_bf16.h>

// Problem constants (from reference): N_NODES=100000, N_EDGES=3200000, D_FEAT=64
#define D_FEAT 64

// One wave (64 lanes) per edge. lane = feature index.
// Coalesced 256B gather from inputs[col], coalesced 256B atomic scatter to out[row].
__global__ void __launch_bounds__(256) edge_scatter_kernel(
    const float* __restrict__ x,     // [N, 64]
    const int* __restrict__ rows,    // [E]
    const int* __restrict__ cols,    // [E]
    float* __restrict__ out,         // [N, 64] (pre-zeroed)
    int* __restrict__ deg,           // [N] (pre-zeroed)
    int n_edges)
{
    const int wave = (blockIdx.x * blockDim.x + threadIdx.x) >> 6;
    const int lane = threadIdx.x & 63;
    if (wave >= n_edges) return;

    const int r = rows[wave];   // wave-uniform (all lanes same address -> 1 request)
    const int c = cols[wave];

    const float v = x[(long)c * D_FEAT + lane];
    // HW fp32 atomic (global_atomic_add_f32), not a CAS loop:
    unsafeAtomicAdd(&out[(long)r * D_FEAT + lane], v);

    if (lane == 0) atomicAdd(&deg[r], 1);
}

// Divide each row by max(deg, 1). float4-vectorized: thread t handles node t>>4,
// features 4*(t&15) .. 4*(t&15)+3.
__global__ void __launch_bounds__(256) divide_kernel(
    float* __restrict__ out,         // [N, 64]
    const int* __restrict__ deg,     // [N]
    int n_nodes)
{
    const int t = blockIdx.x * blockDim.x + threadIdx.x;
    const int total = n_nodes * (D_FEAT / 4);
    if (t >= total) return;
    const int n = t >> 4;                 // 16 float4 per node
    const int d = deg[n];
    const float inv = 1.0f / (float)(d > 0 ? d : 1);
    float4* o4 = (float4*)out;
    float4 v = o4[t];
    v.x *= inv; v.y *= inv; v.z *= inv; v.w *= inv;
    o4[t] = v;
}

extern "C" void kernel_launch(void* const* d_in, const int* in_sizes, int n_in,
                              void* d_out, int out_size, void* d_ws, size_t ws_size,
                              hipStream_t stream) {
    const float* x   = (const float*)d_in[0];   // [N, 64] fp32
    const int* rows  = (const int*)d_in[1];     // [E]
    const int* cols  = (const int*)d_in[2];     // [E]
    float* out = (float*)d_out;

    const int n_nodes = in_sizes[0] / D_FEAT;
    const int n_edges = in_sizes[1];

    int* deg = (int*)d_ws;                      // [N] scratch

    // d_out and d_ws are poisoned with 0xAA before every call — zero them.
    hipMemsetAsync(out, 0, (size_t)n_nodes * D_FEAT * sizeof(float), stream);
    hipMemsetAsync(deg, 0, (size_t)n_nodes * sizeof(int), stream);

    // Scatter: one wave per edge, 4 waves per 256-thread block.
    {
        const long total_threads = (long)n_edges * 64;
        const int blocks = (int)((total_threads + 255) / 256);
        edge_scatter_kernel<<<blocks, 256, 0, stream>>>(x, rows, cols, out, deg, n_edges);
    }

    // Divide by degree.
    {
        const int total = n_nodes * (D_FEAT / 4);
        const int blocks = (total + 255) / 256;
        divide_kernel<<<blocks, 256, 0, stream>>>(out, deg, n_nodes);
    }
}

// Round 2
// 589.056 us; speedup vs baseline: 1.5320x; 1.5320x over previous
//
#include <hip/hip_runtime.h>
#include <hip/hip_bf16.h>

#define D_FEAT 64

// ---------------- Phase A: degree histogram ----------------
__global__ void __launch_bounds__(256) deg_kernel(
    const int* __restrict__ rows, int* __restrict__ deg, int n_edges)
{
    int e = blockIdx.x * blockDim.x + threadIdx.x;
    if (e < n_edges) atomicAdd(&deg[rows[e]], 1);
}

// ---------------- Phase B: exclusive scan of deg -> offs ----------------
// B1: per-block scan of 1024 elements (256 threads x 4), write local-exclusive
// prefixes to offs[] and block total to bsums[b].
__global__ void __launch_bounds__(256) scan1_kernel(
    const int* __restrict__ deg, int* __restrict__ offs,
    int* __restrict__ bsums, int n)
{
    __shared__ int lds[256];
    const int t = threadIdx.x;
    const int base = blockIdx.x * 1024 + t * 4;

    int v[4];
    #pragma unroll
    for (int i = 0; i < 4; ++i) v[i] = (base + i < n) ? deg[base + i] : 0;
    int s = v[0] + v[1] + v[2] + v[3];

    lds[t] = s;
    __syncthreads();
    // Hillis-Steele inclusive scan over 256
    for (int ofs = 1; ofs < 256; ofs <<= 1) {
        int val = lds[t];
        int add = (t >= ofs) ? lds[t - ofs] : 0;
        __syncthreads();
        lds[t] = val + add;
        __syncthreads();
    }
    int excl = lds[t] - s;   // exclusive prefix of this thread's 4-chunk
    if (t == 255) bsums[blockIdx.x] = lds[255];

    int run = excl;
    #pragma unroll
    for (int i = 0; i < 4; ++i) {
        if (base + i < n) offs[base + i] = run;
        run += v[i];
    }
}

// B2: scan the (<=128) block sums in one block.
__global__ void __launch_bounds__(128) scan2_kernel(int* __restrict__ bsums, int nb)
{
    __shared__ int lds[128];
    const int t = threadIdx.x;
    int v = (t < nb) ? bsums[t] : 0;
    lds[t] = v;
    __syncthreads();
    for (int ofs = 1; ofs < 128; ofs <<= 1) {
        int val = lds[t];
        int add = (t >= ofs) ? lds[t - ofs] : 0;
        __syncthreads();
        lds[t] = val + add;
        __syncthreads();
    }
    if (t < nb) bsums[t] = lds[t] - v;  // exclusive
}

// B3: add block offsets, init cursor, set offs[n] = E.
__global__ void __launch_bounds__(256) scan3_kernel(
    int* __restrict__ offs, int* __restrict__ cursor,
    const int* __restrict__ bsums, int n, int n_edges)
{
    int i = blockIdx.x * blockDim.x + threadIdx.x;
    if (i < n) {
        int o = offs[i] + bsums[i >> 10];
        offs[i] = o;
        cursor[i] = o;
    }
    if (i == 0) offs[n] = n_edges;
}

// ---------------- Phase C: fill CSR cols ----------------
__global__ void __launch_bounds__(256) fill_kernel(
    const int* __restrict__ rows, const int* __restrict__ cols,
    int* __restrict__ cursor, int* __restrict__ csr, int n_edges)
{
    int e = blockIdx.x * blockDim.x + threadIdx.x;
    if (e < n_edges) {
        int r = rows[e];
        int pos = atomicAdd(&cursor[r], 1);
        csr[pos] = cols[e];
    }
}

// ---------------- Phase D: per-row gather-sum + divide ----------------
// One wave per row, lane = feature index.
__global__ void __launch_bounds__(256) gather_kernel(
    const float* __restrict__ x, const int* __restrict__ offs,
    const int* __restrict__ csr, float* __restrict__ out, int n_nodes)
{
    const int wave = (blockIdx.x * blockDim.x + threadIdx.x) >> 6;
    const int lane = threadIdx.x & 63;
    if (wave >= n_nodes) return;

    const int s = offs[wave];
    const int e = offs[wave + 1];
    float acc = 0.0f;

    int j = s;
    for (; j + 3 < e; j += 4) {
        int c0 = csr[j], c1 = csr[j + 1], c2 = csr[j + 2], c3 = csr[j + 3];
        acc += x[(long)c0 * D_FEAT + lane];
        acc += x[(long)c1 * D_FEAT + lane];
        acc += x[(long)c2 * D_FEAT + lane];
        acc += x[(long)c3 * D_FEAT + lane];
    }
    for (; j < e; ++j) acc += x[(long)csr[j] * D_FEAT + lane];

    const int d = e - s;
    const float inv = 1.0f / (float)(d > 0 ? d : 1);
    out[(long)wave * D_FEAT + lane] = acc * inv;
}

extern "C" void kernel_launch(void* const* d_in, const int* in_sizes, int n_in,
                              void* d_out, int out_size, void* d_ws, size_t ws_size,
                              hipStream_t stream) {
    const float* x  = (const float*)d_in[0];
    const int* rows = (const int*)d_in[1];
    const int* cols = (const int*)d_in[2];
    float* out = (float*)d_out;

    const int n_nodes = in_sizes[0] / D_FEAT;
    const int n_edges = in_sizes[1];
    const int nb = (n_nodes + 1023) / 1024;   // scan blocks (98 for 100K)

    // Workspace layout (ints): deg[n] | offs[n+1] | cursor[n] | bsums[128] | csr[E]
    int* deg    = (int*)d_ws;
    int* offs   = deg + n_nodes;
    int* cursor = offs + n_nodes + 1;
    int* bsums  = cursor + n_nodes;
    int* csr    = bsums + 128;

    // Only deg needs zeroing (everything else is fully overwritten).
    hipMemsetAsync(deg, 0, (size_t)n_nodes * sizeof(int), stream);

    const int eblocks = (n_edges + 255) / 256;
    deg_kernel<<<eblocks, 256, 0, stream>>>(rows, deg, n_edges);

    scan1_kernel<<<nb, 256, 0, stream>>>(deg, offs, bsums, n_nodes);
    scan2_kernel<<<1, 128, 0, stream>>>(bsums, nb);
    scan3_kernel<<<(n_nodes + 255) / 256, 256, 0, stream>>>(offs, cursor, bsums, n_nodes, n_edges);

    fill_kernel<<<eblocks, 256, 0, stream>>>(rows, cols, cursor, csr, n_edges);

    const long gthreads = (long)n_nodes * 64;
    gather_kernel<<<(int)((gthreads + 255) / 256), 256, 0, stream>>>(x, offs, csr, out, n_nodes);
}

// Round 3
// 287.575 us; speedup vs baseline: 3.1382x; 2.0484x over previous
//
#include <hip/hip_runtime.h>
#include <hip/hip_bf16.h>

#define D_FEAT 64
#define TILE_EDGES 16384        // 256 threads x 64 edges
#define EPT 64
#define ROWS_PER_BUK 128
#define BUK_SHIFT 7
#define CAP 8192                // LDS edge buffer per bucket (avg ~4096, 64-sigma headroom)

// ---------- Phase 1: per-tile histogram over row-buckets (LDS atomics only) ----------
// hist layout: [bucket][ntiles]
__global__ void __launch_bounds__(256) hist_kernel(
    const int* __restrict__ rows, int* __restrict__ hist,
    int n_edges, int nbuk, int ntiles)
{
    __shared__ int lh[1024];
    const int t = threadIdx.x;
    for (int i = t; i < nbuk; i += 256) lh[i] = 0;
    __syncthreads();
    const int base = blockIdx.x * TILE_EDGES;
    #pragma unroll 4
    for (int i = 0; i < EPT; ++i) {
        int e = base + i * 256 + t;
        if (e < n_edges) atomicAdd(&lh[rows[e] >> BUK_SHIFT], 1);
    }
    __syncthreads();
    for (int b = t; b < nbuk; b += 256)
        hist[b * ntiles + blockIdx.x] = lh[b];
}

// ---------- Phase 2: exclusive scan over hist[nbuk*ntiles] (in-place) ----------
__global__ void __launch_bounds__(256) scan1_kernel(
    int* __restrict__ a, int* __restrict__ bsums, int n)
{
    __shared__ int lds[256];
    const int t = threadIdx.x;
    const int base = blockIdx.x * 1024 + t * 4;

    int v[4];
    #pragma unroll
    for (int i = 0; i < 4; ++i) v[i] = (base + i < n) ? a[base + i] : 0;
    int s = v[0] + v[1] + v[2] + v[3];

    lds[t] = s;
    __syncthreads();
    for (int ofs = 1; ofs < 256; ofs <<= 1) {
        int val = lds[t];
        int add = (t >= ofs) ? lds[t - ofs] : 0;
        __syncthreads();
        lds[t] = val + add;
        __syncthreads();
    }
    int excl = lds[t] - s;
    if (t == 255) bsums[blockIdx.x] = lds[255];

    int run = excl;
    #pragma unroll
    for (int i = 0; i < 4; ++i) {
        if (base + i < n) a[base + i] = run;
        run += v[i];
    }
}

__global__ void __launch_bounds__(256) scan2_kernel(int* __restrict__ bsums, int nb)
{
    __shared__ int lds[256];
    const int t = threadIdx.x;
    int v = (t < nb) ? bsums[t] : 0;
    lds[t] = v;
    __syncthreads();
    for (int ofs = 1; ofs < 256; ofs <<= 1) {
        int val = lds[t];
        int add = (t >= ofs) ? lds[t - ofs] : 0;
        __syncthreads();
        lds[t] = val + add;
        __syncthreads();
    }
    if (t < nb) bsums[t] = lds[t] - v;
}

__global__ void __launch_bounds__(256) scan3_kernel(
    int* __restrict__ a, const int* __restrict__ bsums, int n)
{
    int i = blockIdx.x * blockDim.x + threadIdx.x;
    if (i < n) a[i] += bsums[i >> 10];
}

// ---------- Phase 3: scatter packed edges into bucket runs (LDS cursors) ----------
__global__ void __launch_bounds__(256) scatter_kernel(
    const int* __restrict__ rows, const int* __restrict__ cols,
    const int* __restrict__ base, int* __restrict__ ebuf,
    int n_edges, int nbuk, int ntiles)
{
    __shared__ int cur[1024];
    const int t = threadIdx.x;
    for (int b = t; b < nbuk; b += 256)
        cur[b] = base[b * ntiles + blockIdx.x];
    __syncthreads();
    const int tb = blockIdx.x * TILE_EDGES;
    #pragma unroll 4
    for (int i = 0; i < EPT; ++i) {
        int e = tb + i * 256 + t;
        if (e < n_edges) {
            int r = rows[e], c = cols[e];
            int pos = atomicAdd(&cur[r >> BUK_SHIFT], 1);
            ebuf[pos] = ((r & (ROWS_PER_BUK - 1)) << 17) | c;  // col < 2^17
        }
    }
}

// ---------- Phase 4: per-bucket CSR build (LDS staging, in-place rewrite) ----------
__global__ void __launch_bounds__(256) build_kernel(
    const int* __restrict__ scanned, int* __restrict__ ebuf,
    int* __restrict__ offs, int n_nodes, int n_edges, int nbuk, int ntiles)
{
    __shared__ int led[CAP];
    __shared__ int lh[ROWS_PER_BUK];
    __shared__ int lscan[ROWS_PER_BUK];
    __shared__ int lcur[ROWS_PER_BUK];
    const int b = blockIdx.x;
    const int t = threadIdx.x;
    const int start = scanned[b * ntiles];
    const int end = (b + 1 < nbuk) ? scanned[(b + 1) * ntiles] : n_edges;
    int cnt = end - start;
    if (cnt > CAP) cnt = CAP;   // statistically impossible; prevents LDS OOB

    for (int i = t; i < cnt; i += 256) led[i] = ebuf[start + i];
    if (t < ROWS_PER_BUK) lh[t] = 0;
    __syncthreads();
    for (int i = t; i < cnt; i += 256) atomicAdd(&lh[led[i] >> 17], 1);
    __syncthreads();

    // exclusive scan of lh[128]
    int v = (t < ROWS_PER_BUK) ? lh[t] : 0;
    if (t < ROWS_PER_BUK) lscan[t] = v;
    __syncthreads();
    for (int ofs = 1; ofs < ROWS_PER_BUK; ofs <<= 1) {
        int val = 0;
        if (t < ROWS_PER_BUK) {
            val = lscan[t];
            if (t >= ofs) val += lscan[t - ofs];
        }
        __syncthreads();
        if (t < ROWS_PER_BUK) lscan[t] = val;
        __syncthreads();
    }
    const int lo = b << BUK_SHIFT;
    if (t < ROWS_PER_BUK) {
        int excl = lscan[t] - v;
        lcur[t] = excl;
        if (lo + t < n_nodes) offs[lo + t] = start + excl;
    }
    __syncthreads();

    // in-place rewrite: all source data already staged in LDS
    for (int i = t; i < cnt; i += 256) {
        int p = led[i];
        int pos = atomicAdd(&lcur[p >> 17], 1);
        ebuf[start + pos] = p & 0x1FFFF;   // pure col index
    }
    if (b == 0 && t == 0) offs[n_nodes] = n_edges;
}

// ---------- Phase 5: per-row gather-sum + divide (one wave per row) ----------
__global__ void __launch_bounds__(256) gather_kernel(
    const float* __restrict__ x, const int* __restrict__ offs,
    const int* __restrict__ csr, float* __restrict__ out, int n_nodes)
{
    const int wave = (blockIdx.x * blockDim.x + threadIdx.x) >> 6;
    const int lane = threadIdx.x & 63;
    if (wave >= n_nodes) return;

    const int s = offs[wave];
    const int e = offs[wave + 1];
    float acc = 0.0f;

    int j = s;
    for (; j + 3 < e; j += 4) {
        int c0 = csr[j], c1 = csr[j + 1], c2 = csr[j + 2], c3 = csr[j + 3];
        acc += x[(long)c0 * D_FEAT + lane];
        acc += x[(long)c1 * D_FEAT + lane];
        acc += x[(long)c2 * D_FEAT + lane];
        acc += x[(long)c3 * D_FEAT + lane];
    }
    for (; j < e; ++j) acc += x[(long)csr[j] * D_FEAT + lane];

    const int d = e - s;
    const float inv = 1.0f / (float)(d > 0 ? d : 1);
    out[(long)wave * D_FEAT + lane] = acc * inv;
}

extern "C" void kernel_launch(void* const* d_in, const int* in_sizes, int n_in,
                              void* d_out, int out_size, void* d_ws, size_t ws_size,
                              hipStream_t stream) {
    const float* x  = (const float*)d_in[0];
    const int* rows = (const int*)d_in[1];
    const int* cols = (const int*)d_in[2];
    float* out = (float*)d_out;

    const int n_nodes = in_sizes[0] / D_FEAT;
    const int n_edges = in_sizes[1];

    const int nbuk   = (n_nodes + ROWS_PER_BUK - 1) >> BUK_SHIFT;       // 782
    const int ntiles = (n_edges + TILE_EDGES - 1) / TILE_EDGES;         // 196
    const int hn     = nbuk * ntiles;                                   // 153272
    const int nb1    = (hn + 1023) / 1024;                              // 150 (<=256)

    // ws layout (ints): hist[hn] | bsums[256] | offs[n+1] | ebuf[E]
    int* hist  = (int*)d_ws;
    int* bsums = hist + hn;
    int* offs  = bsums + 256;
    int* ebuf  = offs + n_nodes + 1;

    hist_kernel<<<ntiles, 256, 0, stream>>>(rows, hist, n_edges, nbuk, ntiles);

    scan1_kernel<<<nb1, 256, 0, stream>>>(hist, bsums, hn);
    scan2_kernel<<<1, 256, 0, stream>>>(bsums, nb1);
    scan3_kernel<<<(hn + 255) / 256, 256, 0, stream>>>(hist, bsums, hn);

    scatter_kernel<<<ntiles, 256, 0, stream>>>(rows, cols, hist, ebuf, n_edges, nbuk, ntiles);

    build_kernel<<<nbuk, 256, 0, stream>>>(hist, ebuf, offs, n_nodes, n_edges, nbuk, ntiles);

    const long gthreads = (long)n_nodes * 64;
    gather_kernel<<<(int)((gthreads + 255) / 256), 256, 0, stream>>>(x, offs, ebuf, out, n_nodes);
}